// Round 1
// 261.363 us; speedup vs baseline: 1.0321x; 1.0321x over previous
//
#include <hip/hip_runtime.h>

// MultiHashtable4d: 16-level 4D hash-grid interpolation.
// One thread per (point n, level l); l is wave-uniform so per-level params are
// scalar and the direct/hash branch is uniform.
//
// R2: XCD-pinned level-major mapping (blockIdx%8 == level%8) keeps one 4.19MB
//     table per XCD-L2 -> FETCH 902->242MB, 321->193us.
// R3: explicit phase structure (addresses -> 16 live loads -> weights -> FMA).
//     Neutral: cap is a shared per-CU resource (MSHR x latency), not per-wave MLP.
// R4: table owns L2: streaming xyz/t/out marked nontemporal. FETCH ~compulsory.
// R5: kernel sits exactly at concurrency*latency floor: 0.30 gathers/cy/CU
//     x ~215cy L2-hit = ~64 outstanding lines/CU (TCP MSHR-pool-shaped).
//     Gathers have ~0% L1 hit rate (4.19MB random table vs 32KB L1) but still
//     allocate L1 miss-tracking. Bypass L1 with sc0 (SE-scope) loads: issue
//     straight to XCD-L2 (which keeps caching the table), via inline asm
//     global_load_dwordx2 ... sc0 with wave-uniform SGPR base + 32b voffset.

#define FDIM 2

using f32x2 = __attribute__((ext_vector_type(2))) float;

__global__ __launch_bounds__(256) void mh4d_kernel(
    const float* __restrict__ xyz,     // [N,3]
    const float* __restrict__ tt,      // [N,1]
    const float* __restrict__ data,    // [L,T,FDIM]
    const float* __restrict__ bounds,  // [2,4]
    const float* __restrict__ es,      // [L,4] entrys_size
    const int*   __restrict__ en,      // [L,4] entrys_num
    const int*   __restrict__ p_sh,    // start_hash
    const int*   __restrict__ p_sf,    // start_frame
    const int*   __restrict__ p_tf,    // total_frame
    float* __restrict__ out,           // [N, L*FDIM]
    int N, int L, unsigned int T, unsigned long long M,
    unsigned int bpl)                  // blocks per level
{
    int l, chunk;
    if ((L & 7) == 0) {
        // XCD-pinned decode: x = b%8 selects the XCD *and* the level group.
        const unsigned int x   = blockIdx.x & 7u;
        const unsigned int rem = blockIdx.x >> 3;
        const unsigned int p   = rem / bpl;      // phase: which level on this XCD
        chunk = (int)(rem - p * bpl);
        l     = (int)(p * 8u + x);
    } else {
        l     = (int)(blockIdx.x / bpl);
        chunk = (int)(blockIdx.x - (unsigned)l * bpl);
    }
    const int n = chunk * (int)blockDim.x + (int)threadIdx.x;
    if (n >= N) return;

    const int start_hash = *p_sh;
    // reference: t - start_frame/(total_frame-1), scalar rounded to f32
    const float tshift = (float)((double)(*p_sf) / (double)(*p_tf - 1));

    // wave-uniform per-level params -> scalar loads
    const float es0 = es[l * 4 + 0], es1 = es[l * 4 + 1];
    const float es2 = es[l * 4 + 2], es3 = es[l * 4 + 3];
    const int e0 = en[l * 4 + 0], e1 = en[l * 4 + 1];
    const int e2 = en[l * 4 + 2], e3 = en[l * 4 + 3];

    const float b0 = bounds[0], b1 = bounds[1], b2 = bounds[2], b3 = bounds[3];

    // streaming inputs: nontemporal — do not let them evict table lines in L2
    const float x  = __builtin_nontemporal_load(&xyz[n * 3 + 0]);
    const float y  = __builtin_nontemporal_load(&xyz[n * 3 + 1]);
    const float z  = __builtin_nontemporal_load(&xyz[n * 3 + 2]);
    const float tv = __builtin_nontemporal_load(&tt[n]) - tshift;

    // float_xyzt = (xyzt - bounds[0]) / entrys_size  (IEEE f32 div, matches ref)
    const float f0 = (x  - b0) / es0;
    const float f1 = (y  - b1) / es1;
    const float f2 = (z  - b2) / es2;
    const float f3 = (tv - b3) / es3;

    // Corner ints: trunc(f + offset) computed IN f32 — must NOT fold to trunc(f)+1,
    // because f32 rounding of (f+1.0f) near integers changes the index like the ref does.
    int lo0 = (int)f0, hi0 = (int)(f0 + 1.0f);
    int lo1 = (int)f1, hi1 = (int)(f1 + 1.0f);
    int lo2 = (int)f2, hi2 = (int)(f2 + 1.0f);
    int lo3 = (int)f3, hi3 = (int)(f3 + 1.0f);

    // offsets from UNCLIPPED corner-0 trunc (ref computes offset before clip)
    const float o0 = f0 - (float)lo0;
    const float o1 = f1 - (float)lo1;
    const float o2 = f2 - (float)lo2;
    const float o3 = f3 - (float)lo3;

    // clip indices to [0, en-1]
    lo0 = min(max(lo0, 0), e0 - 1);  hi0 = min(max(hi0, 0), e0 - 1);
    lo1 = min(max(lo1, 0), e1 - 1);  hi1 = min(max(hi1, 0), e1 - 1);
    lo2 = min(max(lo2, 0), e2 - 1);  hi2 = min(max(hi2, 0), e2 - 1);
    lo3 = min(max(lo3, 0), e3 - 1);  hi3 = min(max(hi3, 0), e3 - 1);

    // ---- Phase 1: all 16 table offsets (elements, not bytes) ----
    unsigned int r16[16];
    if (l >= start_hash) {
        // hash path: xor of 64-bit prime products, mod T via magic multiply
        const unsigned long long hx[2] = { (unsigned long long)(unsigned)lo0,
                                           (unsigned long long)(unsigned)hi0 };
        const unsigned long long hy[2] = { (unsigned long long)(unsigned)lo1 * 19349663ull,
                                           (unsigned long long)(unsigned)hi1 * 19349663ull };
        const unsigned long long hz[2] = { (unsigned long long)(unsigned)lo2 * 83492791ull,
                                           (unsigned long long)(unsigned)hi2 * 83492791ull };
        const unsigned long long ht[2] = { (unsigned long long)(unsigned)lo3 * 73856093ull,
                                           (unsigned long long)(unsigned)hi3 * 73856093ull };
        #pragma unroll
        for (int c = 0; c < 16; ++c) {
            const unsigned long long v =
                hx[(c >> 3) & 1] ^ hy[(c >> 2) & 1] ^ hz[(c >> 1) & 1] ^ ht[c & 1];
            const unsigned long long q = __umul64hi(v, M);   // q in {Q-1, Q}
            unsigned int r = (unsigned int)v - (unsigned int)q * T;  // r in [0, 2T)
            if (r >= T) r -= T;
            r16[c] = r;
        }
    } else {
        // direct path: ((x*e1+y)*e2+z)*e3+t, always < T so 32-bit is exact
        #pragma unroll
        for (int c = 0; c < 16; ++c) {
            const unsigned int ix = (unsigned)((c & 8) ? hi0 : lo0);
            const unsigned int iy = (unsigned)((c & 4) ? hi1 : lo1);
            const unsigned int iz = (unsigned)((c & 2) ? hi2 : lo2);
            const unsigned int it = (unsigned)((c & 1) ? hi3 : lo3);
            unsigned int ind = ix * (unsigned)e1 + iy;
            ind = ind * (unsigned)e2 + iz;
            ind = ind * (unsigned)e3 + it;
            r16[c] = ind;
        }
    }

    // ---- Phase 2: issue ALL 16 gathers, L1-BYPASS (sc0 = SE scope). ----
    // Table stays cached in the XCD L2 (sc1=0); we skip the ~0%-hit-rate
    // per-CU L1 and its miss-tracking pool. Base is wave-uniform -> SGPR pair,
    // per-lane 32-bit byte offset (max 4.19MB, no overflow).
    const float* __restrict__ base = data + (size_t)l * (size_t)T * FDIM;
    f32x2 vals[16];
    #pragma unroll
    for (int c = 0; c < 16; ++c) {
        asm volatile("global_load_dwordx2 %0, %1, %2 sc0"
                     : "=v"(vals[c])
                     : "v"(r16[c] * 8u), "s"(base));
    }

    // ---- Phase 3: weights (VALU work overlapping the in-flight loads) ----
    // clip(1-o,0,1) / clip(o,0,1); hierarchical products ((wx*wy)*wz)*wt
    const float wx[2] = { fminf(fmaxf(1.0f - o0, 0.0f), 1.0f), fminf(fmaxf(o0, 0.0f), 1.0f) };
    const float wy[2] = { fminf(fmaxf(1.0f - o1, 0.0f), 1.0f), fminf(fmaxf(o1, 0.0f), 1.0f) };
    const float wz[2] = { fminf(fmaxf(1.0f - o2, 0.0f), 1.0f), fminf(fmaxf(o2, 0.0f), 1.0f) };
    const float wt[2] = { fminf(fmaxf(1.0f - o3, 0.0f), 1.0f), fminf(fmaxf(o3, 0.0f), 1.0f) };

    float pxy[4], pxyz[8], w16[16];
    #pragma unroll
    for (int a = 0; a < 2; ++a)
        #pragma unroll
        for (int b = 0; b < 2; ++b)
            pxy[a * 2 + b] = wx[a] * wy[b];
    #pragma unroll
    for (int a = 0; a < 4; ++a)
        #pragma unroll
        for (int b = 0; b < 2; ++b)
            pxyz[a * 2 + b] = pxy[a] * wz[b];
    #pragma unroll
    for (int a = 0; a < 8; ++a)
        #pragma unroll
        for (int b = 0; b < 2; ++b)
            w16[a * 2 + b] = pxyz[a] * wt[b];

    // ---- Phase 4: wait for all gathers, then reduce. ----
    // Inline-asm loads are invisible to the compiler's waitcnt insertion:
    // explicit vmcnt(0) + sched_barrier(0) fence (rule-#18 pattern) before use.
    asm volatile("s_waitcnt vmcnt(0)" ::: "memory");
    __builtin_amdgcn_sched_barrier(0);

    float accx = 0.0f, accy = 0.0f;
    #pragma unroll
    for (int c = 0; c < 16; ++c) {
        accx = fmaf(w16[c], vals[c][0], accx);
        accy = fmaf(w16[c], vals[c][1], accy);
    }

    // out[n, l*F .. l*F+1]: nontemporal 8B store — don't pollute L2 with output
    unsigned long long packed =
        ((unsigned long long)__float_as_uint(accy) << 32) | (unsigned long long)__float_as_uint(accx);
    unsigned long long* op =
        (unsigned long long*)(out + ((size_t)n * (size_t)L + (size_t)l) * FDIM);
    __builtin_nontemporal_store(packed, op);
}

extern "C" void kernel_launch(void* const* d_in, const int* in_sizes, int n_in,
                              void* d_out, int out_size, void* d_ws, size_t ws_size,
                              hipStream_t stream) {
    const float* xyz    = (const float*)d_in[0];
    const float* tt     = (const float*)d_in[1];
    const float* data   = (const float*)d_in[2];
    const float* bounds = (const float*)d_in[3];
    // d_in[4] = offsets: the 16 binary corners are hard-coded (matches reference OFFSETS)
    const float* es     = (const float*)d_in[5];
    const int*   en     = (const int*)d_in[6];
    const int*   p_sh   = (const int*)d_in[7];
    const int*   p_sf   = (const int*)d_in[8];
    const int*   p_tf   = (const int*)d_in[9];
    float*       out    = (float*)d_out;

    const int N = in_sizes[0] / 3;
    const int L = in_sizes[5] / 4;                       // entrys_size is [L,4]
    const unsigned int T = (unsigned int)(in_sizes[2] / (L * FDIM)); // data is [L,T,F]
    const unsigned long long M = ~0ull / (unsigned long long)T;      // floor(2^64/T), T prime

    const int threads = 256;
    const unsigned int bpl = (unsigned)((N + threads - 1) / threads); // blocks per level
    dim3 grid(bpl * (unsigned)L);
    mh4d_kernel<<<grid, threads, 0, stream>>>(xyz, tt, data, bounds, es, en,
                                              p_sh, p_sf, p_tf, out,
                                              N, L, T, M, bpl);
}

// Round 2
// 261.264 us; speedup vs baseline: 1.0324x; 1.0004x over previous
//
#include <hip/hip_runtime.h>

// MultiHashtable4d: 16-level 4D hash-grid interpolation.
// One thread per (point n, level l); l is wave-uniform so per-level params are
// scalar and the direct/hash branch is uniform.
//
// R2: XCD-pinned level-major mapping (blockIdx%8 == level%8) keeps one 4.19MB
//     table per XCD-L2 -> FETCH 902->242MB, 321->193us.
// R3: explicit phase structure (addresses -> 16 live loads -> weights -> FMA).
//     Neutral: cap is a shared per-CU resource (MSHR x latency), not per-wave MLP.
// R4: table owns L2: streaming xyz/t/out marked nontemporal. FETCH ~compulsory.
// R5: sc0 (L1-bypass) on all gathers: -2.7%. Concurrency cap unchanged at
//     ~0.30 line-req/cy/CU = ~64 outstanding x ~215cy L2-hit. The cap survives
//     phase restructure (R3), L2 policy (R4), and L1 bypass (R5).
// R6: TEST: are the L1-miss MSHR pool and the sc0-bypass queue SEPARATE
//     tracking resources? R0 ran 100% cached, R1 ran 100% sc0 — each leaves
//     the other pool idle. Split gathers 8/8 across both paths. If pools are
//     separate -> ~2x outstanding -> dur ~110-140us. If unified -> null.

#define FDIM 2

using f32x2 = __attribute__((ext_vector_type(2))) float;

__global__ __launch_bounds__(256) void mh4d_kernel(
    const float* __restrict__ xyz,     // [N,3]
    const float* __restrict__ tt,      // [N,1]
    const float* __restrict__ data,    // [L,T,FDIM]
    const float* __restrict__ bounds,  // [2,4]
    const float* __restrict__ es,      // [L,4] entrys_size
    const int*   __restrict__ en,      // [L,4] entrys_num
    const int*   __restrict__ p_sh,    // start_hash
    const int*   __restrict__ p_sf,    // start_frame
    const int*   __restrict__ p_tf,    // total_frame
    float* __restrict__ out,           // [N, L*FDIM]
    int N, int L, unsigned int T, unsigned long long M,
    unsigned int bpl)                  // blocks per level
{
    int l, chunk;
    if ((L & 7) == 0) {
        // XCD-pinned decode: x = b%8 selects the XCD *and* the level group.
        const unsigned int x   = blockIdx.x & 7u;
        const unsigned int rem = blockIdx.x >> 3;
        const unsigned int p   = rem / bpl;      // phase: which level on this XCD
        chunk = (int)(rem - p * bpl);
        l     = (int)(p * 8u + x);
    } else {
        l     = (int)(blockIdx.x / bpl);
        chunk = (int)(blockIdx.x - (unsigned)l * bpl);
    }
    const int n = chunk * (int)blockDim.x + (int)threadIdx.x;
    if (n >= N) return;

    const int start_hash = *p_sh;
    // reference: t - start_frame/(total_frame-1), scalar rounded to f32
    const float tshift = (float)((double)(*p_sf) / (double)(*p_tf - 1));

    // wave-uniform per-level params -> scalar loads
    const float es0 = es[l * 4 + 0], es1 = es[l * 4 + 1];
    const float es2 = es[l * 4 + 2], es3 = es[l * 4 + 3];
    const int e0 = en[l * 4 + 0], e1 = en[l * 4 + 1];
    const int e2 = en[l * 4 + 2], e3 = en[l * 4 + 3];

    const float b0 = bounds[0], b1 = bounds[1], b2 = bounds[2], b3 = bounds[3];

    // streaming inputs: nontemporal — do not let them evict table lines in L2
    const float x  = __builtin_nontemporal_load(&xyz[n * 3 + 0]);
    const float y  = __builtin_nontemporal_load(&xyz[n * 3 + 1]);
    const float z  = __builtin_nontemporal_load(&xyz[n * 3 + 2]);
    const float tv = __builtin_nontemporal_load(&tt[n]) - tshift;

    // float_xyzt = (xyzt - bounds[0]) / entrys_size  (IEEE f32 div, matches ref)
    const float f0 = (x  - b0) / es0;
    const float f1 = (y  - b1) / es1;
    const float f2 = (z  - b2) / es2;
    const float f3 = (tv - b3) / es3;

    // Corner ints: trunc(f + offset) computed IN f32 — must NOT fold to trunc(f)+1,
    // because f32 rounding of (f+1.0f) near integers changes the index like the ref does.
    int lo0 = (int)f0, hi0 = (int)(f0 + 1.0f);
    int lo1 = (int)f1, hi1 = (int)(f1 + 1.0f);
    int lo2 = (int)f2, hi2 = (int)(f2 + 1.0f);
    int lo3 = (int)f3, hi3 = (int)(f3 + 1.0f);

    // offsets from UNCLIPPED corner-0 trunc (ref computes offset before clip)
    const float o0 = f0 - (float)lo0;
    const float o1 = f1 - (float)lo1;
    const float o2 = f2 - (float)lo2;
    const float o3 = f3 - (float)lo3;

    // clip indices to [0, en-1]
    lo0 = min(max(lo0, 0), e0 - 1);  hi0 = min(max(hi0, 0), e0 - 1);
    lo1 = min(max(lo1, 0), e1 - 1);  hi1 = min(max(hi1, 0), e1 - 1);
    lo2 = min(max(lo2, 0), e2 - 1);  hi2 = min(max(hi2, 0), e2 - 1);
    lo3 = min(max(lo3, 0), e3 - 1);  hi3 = min(max(hi3, 0), e3 - 1);

    // ---- Phase 1: all 16 table offsets (elements, not bytes) ----
    unsigned int r16[16];
    if (l >= start_hash) {
        // hash path: xor of 64-bit prime products, mod T via magic multiply
        const unsigned long long hx[2] = { (unsigned long long)(unsigned)lo0,
                                           (unsigned long long)(unsigned)hi0 };
        const unsigned long long hy[2] = { (unsigned long long)(unsigned)lo1 * 19349663ull,
                                           (unsigned long long)(unsigned)hi1 * 19349663ull };
        const unsigned long long hz[2] = { (unsigned long long)(unsigned)lo2 * 83492791ull,
                                           (unsigned long long)(unsigned)hi2 * 83492791ull };
        const unsigned long long ht[2] = { (unsigned long long)(unsigned)lo3 * 73856093ull,
                                           (unsigned long long)(unsigned)hi3 * 73856093ull };
        #pragma unroll
        for (int c = 0; c < 16; ++c) {
            const unsigned long long v =
                hx[(c >> 3) & 1] ^ hy[(c >> 2) & 1] ^ hz[(c >> 1) & 1] ^ ht[c & 1];
            const unsigned long long q = __umul64hi(v, M);   // q in {Q-1, Q}
            unsigned int r = (unsigned int)v - (unsigned int)q * T;  // r in [0, 2T)
            if (r >= T) r -= T;
            r16[c] = r;
        }
    } else {
        // direct path: ((x*e1+y)*e2+z)*e3+t, always < T so 32-bit is exact
        #pragma unroll
        for (int c = 0; c < 16; ++c) {
            const unsigned int ix = (unsigned)((c & 8) ? hi0 : lo0);
            const unsigned int iy = (unsigned)((c & 4) ? hi1 : lo1);
            const unsigned int iz = (unsigned)((c & 2) ? hi2 : lo2);
            const unsigned int it = (unsigned)((c & 1) ? hi3 : lo3);
            unsigned int ind = ix * (unsigned)e1 + iy;
            ind = ind * (unsigned)e2 + iz;
            ind = ind * (unsigned)e3 + it;
            r16[c] = ind;
        }
    }

    // ---- Phase 2: issue ALL 16 gathers, split across BOTH memory paths. ----
    // Even corners: sc0 (SE scope, L1-bypass -> L2 direct).
    // Odd corners:  default (CU scope, L1-cached miss path).
    // If the bypass queue and the L1-miss MSHR pool are separate per-CU
    // tracking resources, this doubles outstanding-line capacity.
    const float* __restrict__ base = data + (size_t)l * (size_t)T * FDIM;
    f32x2 vals[16];
    #pragma unroll
    for (int c = 0; c < 16; c += 2) {
        asm volatile("global_load_dwordx2 %0, %1, %2 sc0"
                     : "=v"(vals[c])
                     : "v"(r16[c] * 8u), "s"(base));
        asm volatile("global_load_dwordx2 %0, %1, %2"
                     : "=v"(vals[c + 1])
                     : "v"(r16[c + 1] * 8u), "s"(base));
    }

    // ---- Phase 3: weights (VALU work overlapping the in-flight loads) ----
    // clip(1-o,0,1) / clip(o,0,1); hierarchical products ((wx*wy)*wz)*wt
    const float wx[2] = { fminf(fmaxf(1.0f - o0, 0.0f), 1.0f), fminf(fmaxf(o0, 0.0f), 1.0f) };
    const float wy[2] = { fminf(fmaxf(1.0f - o1, 0.0f), 1.0f), fminf(fmaxf(o1, 0.0f), 1.0f) };
    const float wz[2] = { fminf(fmaxf(1.0f - o2, 0.0f), 1.0f), fminf(fmaxf(o2, 0.0f), 1.0f) };
    const float wt[2] = { fminf(fmaxf(1.0f - o3, 0.0f), 1.0f), fminf(fmaxf(o3, 0.0f), 1.0f) };

    float pxy[4], pxyz[8], w16[16];
    #pragma unroll
    for (int a = 0; a < 2; ++a)
        #pragma unroll
        for (int b = 0; b < 2; ++b)
            pxy[a * 2 + b] = wx[a] * wy[b];
    #pragma unroll
    for (int a = 0; a < 4; ++a)
        #pragma unroll
        for (int b = 0; b < 2; ++b)
            pxyz[a * 2 + b] = pxy[a] * wz[b];
    #pragma unroll
    for (int a = 0; a < 8; ++a)
        #pragma unroll
        for (int b = 0; b < 2; ++b)
            w16[a * 2 + b] = pxyz[a] * wt[b];

    // ---- Phase 4: wait for all gathers, then reduce. ----
    // Inline-asm loads are invisible to the compiler's waitcnt insertion:
    // explicit vmcnt(0) + sched_barrier(0) fence (rule-#18 pattern) before use.
    asm volatile("s_waitcnt vmcnt(0)" ::: "memory");
    __builtin_amdgcn_sched_barrier(0);

    float accx = 0.0f, accy = 0.0f;
    #pragma unroll
    for (int c = 0; c < 16; ++c) {
        accx = fmaf(w16[c], vals[c][0], accx);
        accy = fmaf(w16[c], vals[c][1], accy);
    }

    // out[n, l*F .. l*F+1]: nontemporal 8B store — don't pollute L2 with output
    unsigned long long packed =
        ((unsigned long long)__float_as_uint(accy) << 32) | (unsigned long long)__float_as_uint(accx);
    unsigned long long* op =
        (unsigned long long*)(out + ((size_t)n * (size_t)L + (size_t)l) * FDIM);
    __builtin_nontemporal_store(packed, op);
}

extern "C" void kernel_launch(void* const* d_in, const int* in_sizes, int n_in,
                              void* d_out, int out_size, void* d_ws, size_t ws_size,
                              hipStream_t stream) {
    const float* xyz    = (const float*)d_in[0];
    const float* tt     = (const float*)d_in[1];
    const float* data   = (const float*)d_in[2];
    const float* bounds = (const float*)d_in[3];
    // d_in[4] = offsets: the 16 binary corners are hard-coded (matches reference OFFSETS)
    const float* es     = (const float*)d_in[5];
    const int*   en     = (const int*)d_in[6];
    const int*   p_sh   = (const int*)d_in[7];
    const int*   p_sf   = (const int*)d_in[8];
    const int*   p_tf   = (const int*)d_in[9];
    float*       out    = (float*)d_out;

    const int N = in_sizes[0] / 3;
    const int L = in_sizes[5] / 4;                       // entrys_size is [L,4]
    const unsigned int T = (unsigned int)(in_sizes[2] / (L * FDIM)); // data is [L,T,F]
    const unsigned long long M = ~0ull / (unsigned long long)T;      // floor(2^64/T), T prime

    const int threads = 256;
    const unsigned int bpl = (unsigned)((N + threads - 1) / threads); // blocks per level
    dim3 grid(bpl * (unsigned)L);
    mh4d_kernel<<<grid, threads, 0, stream>>>(xyz, tt, data, bounds, es, en,
                                              p_sh, p_sf, p_tf, out,
                                              N, L, T, M, bpl);
}